// Round 11
// baseline (219.627 us; speedup 1.0000x reference)
//
#include <hip/hip_runtime.h>
#include <hip/hip_fp16.h>

// GAT, 2 layers, fp32 in/out. N=50000, E=850000 (incl. self-loops, deg>=1).
// R2: fp32 atomics -> CSR gather design. R8: bucketed CSR, fp16 z1.
// R10 FAILURE: cooperative launch silently no-ops — never use.
// R11 radix partition; R12 pad / R13 ILP / R16 transpose / R19 request-cut:
// ALL NULL. R14 wt->L1: 173.6. REP diagnostics: kg1~35, kg2~23, kA~25,
// kB~5.5 + fill 45 + gaps ~30.
// R20 FAILURE: deterministic 64-slot cells dropped edges — the SELF-LOOP
// TAIL is sequential: one rank's chunk = 4337 consecutive dsts -> ~17
// buckets x 256 edges/cell >> 64. absmax 1.9. Lesson: edge list = 800K
// random + 50K sequential self-loops; cell sizing must cover 256+margin.
// R21 (this round):
//  1. Deterministic cells kept, CAP=512 (pow2; worst cell ~266; 78MB).
//     Still: no global atomics, no memset, 4 dispatches. kB scans cells
//     with wave-uniform skip of the (almost always empty) upper half.
//  2. Occupancy restructure of kg1/kg2 — the surviving model says gathers
//     are rounds x serial-chain (~500cy/iter) bound: old-kg2(50K waves,
//     2 iters, 40%occ) == new-kg2(3128 waves, 17 iters, 28%occ) == 23us.
//     Need MANY resident waves AND short chains: 4 dsts/wave, 16
//     lanes/dst. kg1: 8 heads x 2-way edge split (reduce mask 8).
//     kg2: 4 dims x 4-way edge split (reduce masks 4,8). Grid 782/1563 ->
//     3125 each => ~full device occupancy; chains 17 -> 8.5/4.3.
// Predicted: kg1 ~16-20, kg2 ~9-12, total ~148-158, absmax 0.015625.
// PRE-COMMIT: if >=168 with occupancy visibly up => structure-independent
// floor -> next round in-launch pipeline REP to measure gaps, then likely
// declare roofline.
// NOTE: 44-46us/256MiB fillBufferAligned = harness poison, fixed.
// No shfl inside divergent loops (R3) — only after reconvergence.
// Algebra: sum_e (exp/D)*z == (sum_e exp*z)/D — single pass per dst.

#define LRELU(v) ((v) > 0.f ? (v) : 0.2f * (v))

#define NB   196      // dst-range buckets = ceil(50000/256), bucket = dst>>8
#define CAP  512      // slots per (bucket,rank) cell (worst ~266, R20 lesson)

// ---- Kernel A: fused edge partition + tiled GEMM1 -----------------------
// blocks: b%5==4 -> partition rank b/5 (196 ranks); else GEMM tile
// (b/5)*4 + b%5 (784 slots, 782 used). Interleaving spreads both across
// all XCDs; GEMM VALU hides inside partition's memory stalls.
__global__ void __launch_bounds__(256, 4)
kA(const float* __restrict__ x, const float* __restrict__ W1,
   const float* __restrict__ a_dst1,
   const int* __restrict__ src, const int* __restrict__ dst,
   int* __restrict__ cnts, int* __restrict__ pairs,
   __half* __restrict__ z1h, float* __restrict__ ad1, int N, int E) {
    __shared__ float xs[64][133];   // 133: stride 532 floats = 20 banks mod 32
    __shared__ float avs[64];       // a_dst1
    int b = blockIdx.x;
    int tid = threadIdx.x;
    bool is_part = ((b % 5) == 4);

    if (is_part) {
        // ---- partition path: single pass, deterministic 512-slot cells --
        int* cur = (int*)&xs[0][0];             // 196 LDS counters
        int rank = b / 5;                       // 0..195
        if (tid < NB) cur[tid] = 0;
        __syncthreads();
        int chunk = (E + NB - 1) / NB;          // 4337
        int e0 = rank * chunk;
        int e1 = min(e0 + chunk, E);
        for (int e = e0 + tid; e < e1; e += 256) {
            int d = dst[e], s = src[e];
            int bk = d >> 8;
            int i = atomicAdd(&cur[bk], 1);     // LDS only
            if (i < CAP) pairs[((bk * NB + rank) << 9) + i] = (s << 8) | (d & 255);
        }
        __syncthreads();
        if (tid < NB) cnts[tid * NB + rank] = min(cur[tid], CAP);
        return;
    }

    // ---- GEMM path: 64 nodes x 64 cols, 4x4 register tile per thread ----
    int tile = (b / 5) * 4 + (b % 5);
    if (tile >= 782) return;
    int n0 = tile * 64;
    for (int idx = tid; idx < 2048; idx += 256) {
        int r = idx >> 5, q = idx & 31;
        int n = n0 + r; if (n >= N) n = N - 1;  // clamp; dup rows unused
        float4 v = ((const float4*)(x + (size_t)n * 128))[q];
        *(float4*)&xs[r][q * 4] = v;
    }
    if (tid < 64) avs[tid] = a_dst1[tid];
    __syncthreads();

    int rg = tid >> 4, cg2 = tid & 15;
    int xr = rg * 4;
    // W1 row-major [128][64]: thread reads float4 W1[k][cg2*4..+3] — one
    // 256B row per wave, 4x lane-duplicated -> L1 broadcast (R14).
    const float4* wb = (const float4*)W1 + cg2;   // row k = wb[k*16]
    float acc[4][4] = {};
    float4 xv[4], wl[4];
#pragma unroll
    for (int i = 0; i < 4; ++i) xv[i] = *(const float4*)&xs[xr + i][0];
#pragma unroll
    for (int kk = 0; kk < 4; ++kk) wl[kk] = wb[kk * 16];
#pragma unroll 2
    for (int k4 = 0; k4 < 32; ++k4) {
        float4 xn[4], wn[4];
        int kn = (k4 + 1) & 31;
#pragma unroll
        for (int i = 0; i < 4; ++i) xn[i] = *(const float4*)&xs[xr + i][kn * 4];
#pragma unroll
        for (int kk = 0; kk < 4; ++kk) wn[kk] = wb[(kn * 4 + kk) * 16];
#pragma unroll
        for (int i = 0; i < 4; ++i) {
            acc[i][0] += xv[i].x * wl[0].x; acc[i][1] += xv[i].x * wl[0].y;
            acc[i][2] += xv[i].x * wl[0].z; acc[i][3] += xv[i].x * wl[0].w;
            acc[i][0] += xv[i].y * wl[1].x; acc[i][1] += xv[i].y * wl[1].y;
            acc[i][2] += xv[i].y * wl[1].z; acc[i][3] += xv[i].y * wl[1].w;
            acc[i][0] += xv[i].z * wl[2].x; acc[i][1] += xv[i].z * wl[2].y;
            acc[i][2] += xv[i].z * wl[2].z; acc[i][3] += xv[i].z * wl[2].w;
            acc[i][0] += xv[i].w * wl[3].x; acc[i][1] += xv[i].w * wl[3].y;
            acc[i][2] += xv[i].w * wl[3].z; acc[i][3] += xv[i].w * wl[3].w;
        }
#pragma unroll
        for (int i = 0; i < 4; ++i) { xv[i] = xn[i]; wl[i] = wn[i]; }
    }
    int h = cg2 >> 1, db = (cg2 & 1) * 4;
    float pad_[4];
#pragma unroll
    for (int i = 0; i < 4; ++i) {
        float dd = 0.f;
#pragma unroll
        for (int j = 0; j < 4; ++j) dd += acc[i][j] * avs[h * 8 + db + j];
        pad_[i] = dd;
    }
#pragma unroll
    for (int i = 0; i < 4; ++i)    // pair-reduce cg even/odd (full exec)
        pad_[i] += __shfl_xor(pad_[i], 1, 64);
#pragma unroll
    for (int i = 0; i < 4; ++i) {
        int n = n0 + rg * 4 + i;
        if (n < N) {
            union { __half2 h2[2]; uint2 u; } pk;
            pk.h2[0] = __floats2half2_rn(acc[i][0], acc[i][1]);
            pk.h2[1] = __floats2half2_rn(acc[i][2], acc[i][3]);
            *(uint2*)&z1h[(size_t)n * 64 + cg2 * 4] = pk.u;   // 8B aligned
            if ((cg2 & 1) == 0) ad1[(size_t)n * 8 + h] = pad_[i];
        }
    }
}

// ---- Kernel B: per-bucket CSR build ------------------------------------
// block b owns bucket b: 196 contiguous 512-slot cells (401KB), scanned
// masked by cnts; upper cell half skipped wave-uniformly when count<=256
// (true for all but ~boundary cells). Rank via LDS atomicAdd; scatter csr
// inside single-writer 64KB region; write deg directly.
__global__ void kB(const int* __restrict__ cnts, const int* __restrict__ pairs,
                   int* __restrict__ deg, int* __restrict__ csr, int N) {
    __shared__ int cur[256];
    __shared__ int scnt[NB];
    int b = blockIdx.x;
    int tid = threadIdx.x;
    cur[tid] = 0;
    if (tid < NB) scnt[tid] = cnts[b * NB + tid];
    __syncthreads();
    const int* p = pairs + ((size_t)b * NB << 9);
    for (int it = 0; it < NB * 2; ++it) {       // (cell, half) pairs
        int r = it >> 1, half = it & 1;
        int n = scnt[r];
        if (half && n <= 256) continue;         // wave-uniform skip
        int i = half * 256 + tid;
        if (i < n) {
            int v = p[(r << 9) + i];
            int off = v & 255, s = v >> 8;
            int pos = atomicAdd(&cur[off], 1);
            if (pos < 64) csr[(((b << 8) + off) << 6) + pos] = s;
        }
    }
    __syncthreads();
    int d = (b << 8) + tid;
    if (d < N) deg[d] = cur[tid];
}

// ---- KG1: 4 dsts/wave, 16 lanes/dst = 8 heads x 2-way edge split --------
// lane = (dloc=lane>>4, g=(lane>>3)&1, q=lane&7). Lane accumulates its
// (dst,head) slice over edges j=g,g+2,..; post-loop shfl_xor(8) merges the
// two halves (reconverged — R3-safe). as1 derived in-register (R19);
// packed z2r epilogue (R19); block-cooperative staging (R20).
// Grid 3125 blocks => ~full occupancy; chain ~8.5 iters.
__global__ void kg1(const int* __restrict__ deg, const int* __restrict__ csr,
                    const float* __restrict__ a_src1, const float* __restrict__ ad1,
                    const __half* __restrict__ z1h, const float* __restrict__ b1,
                    const float* __restrict__ W2, const float* __restrict__ a_src2,
                    const float* __restrict__ a_dst2,
                    float* __restrict__ z2r, int N) {
    __shared__ int s_idx[16][65];      // 65: bank spread
    __shared__ int sdeg[16];
    __shared__ float hs[4][4][68];     // 68: dloc*4 bank offset, 16B rows
    __shared__ float ws2[64][18];      // 18: 8B-aligned float2, spread banks
    int tid = threadIdx.x;
    int lane = tid & 63, wid = tid >> 6;
    int blk0 = blockIdx.x * 16;
    for (int i = tid; i < 1024; i += 256) ws2[i >> 4][i & 15] = W2[i];
    for (int idx = tid; idx < 1024; idx += 256) {   // coalesced CSR stage
        int dl = idx >> 6, sl = idx & 63;
        int dr = blk0 + dl; if (dr >= N) dr = N - 1;
        s_idx[dl][sl] = csr[(dr << 6) + sl];
    }
    if (tid < 16) {
        int dr = blk0 + tid; if (dr >= N) dr = N - 1;
        sdeg[tid] = min(deg[dr], 64);
    }
    __syncthreads();

    int dloc = lane >> 4, g = (lane >> 3) & 1, q = lane & 7;
    int dl16 = wid * 4 + dloc;
    int d = blk0 + dl16;
    int dc = d < N ? d : N - 1;
    int cnt = d < N ? sdeg[dl16] : 0;
    float adv = ad1[(size_t)dc * 8 + q];
    float4 asA = *(const float4*)(a_src1 + q * 8);      // a_src1[q][0..3]
    float4 asB = *(const float4*)(a_src1 + q * 8 + 4);  // a_src1[q][4..7]
    float a0 = 0.f, a1 = 0.f, a2 = 0.f, a3 = 0.f;
    float a4 = 0.f, a5 = 0.f, a6 = 0.f, a7 = 0.f, dsum = 0.f;
#pragma unroll 2
    for (int j = g; j < cnt; j += 2) {
        int s = s_idx[dl16][j];                          // group broadcast
        float4 raw = *(const float4*)(z1h + (size_t)s * 64 + q * 8);  // 8 halves
        const __half2* hp = (const __half2*)&raw;
        float2 f0 = __half22float2(hp[0]), f1 = __half22float2(hp[1]);
        float2 f2 = __half22float2(hp[2]), f3 = __half22float2(hp[3]);
        float av = f0.x * asA.x + f0.y * asA.y + f1.x * asA.z + f1.y * asA.w
                 + f2.x * asB.x + f2.y * asB.y + f3.x * asB.z + f3.y * asB.w;
        float ev = av + adv;
        float w = __expf(LRELU(ev));
        a0 += w * f0.x; a1 += w * f0.y; a2 += w * f1.x; a3 += w * f1.y;
        a4 += w * f2.x; a5 += w * f2.y; a6 += w * f3.x; a7 += w * f3.y;
        dsum += w;
    }
    // reconverged; merge the two edge halves (lanes differ in bit 3)
    a0 += __shfl_xor(a0, 8, 64); a1 += __shfl_xor(a1, 8, 64);
    a2 += __shfl_xor(a2, 8, 64); a3 += __shfl_xor(a3, 8, 64);
    a4 += __shfl_xor(a4, 8, 64); a5 += __shfl_xor(a5, 8, 64);
    a6 += __shfl_xor(a6, 8, 64); a7 += __shfl_xor(a7, 8, 64);
    dsum += __shfl_xor(dsum, 8, 64);
    float inv = cnt ? 1.f / dsum : 0.f;
    float4 bv0 = *(const float4*)(b1 + q * 8);
    float4 bv1 = *(const float4*)(b1 + q * 8 + 4);
    float hv[8] = {a0 * inv + bv0.x, a1 * inv + bv0.y,
                   a2 * inv + bv0.z, a3 * inv + bv0.w,
                   a4 * inv + bv1.x, a5 * inv + bv1.y,
                   a6 * inv + bv1.z, a7 * inv + bv1.w};
#pragma unroll
    for (int i = 0; i < 8; ++i) hv[i] = hv[i] > 0.f ? hv[i] : expm1f(hv[i]);
    if (g == 0) {
        *(float4*)&hs[wid][dloc][q * 8]     = make_float4(hv[0], hv[1], hv[2], hv[3]);
        *(float4*)&hs[wid][dloc][q * 8 + 4] = make_float4(hv[4], hv[5], hv[6], hv[7]);
    }
    // hs: same-wave RAW -> no barrier. GEMM2: lane = (dst dloc, colpair q),
    // both g halves compute identical zc (redundant, harmless).
    float zc0 = 0.f, zc1 = 0.f;
#pragma unroll
    for (int k4 = 0; k4 < 16; ++k4) {
        float4 hh = *(const float4*)&hs[wid][dloc][k4 * 4];
        float2 w0 = *(const float2*)&ws2[k4 * 4 + 0][q * 2];
        float2 w1 = *(const float2*)&ws2[k4 * 4 + 1][q * 2];
        float2 w2 = *(const float2*)&ws2[k4 * 4 + 2][q * 2];
        float2 w3 = *(const float2*)&ws2[k4 * 4 + 3][q * 2];
        zc0 += hh.x * w0.x; zc1 += hh.x * w0.y;
        zc0 += hh.y * w1.x; zc1 += hh.y * w1.y;
        zc0 += hh.z * w2.x; zc1 += hh.z * w2.y;
        zc0 += hh.w * w3.x; zc1 += hh.w * w3.y;
    }
    if (g == 0 && d < N)
        *(float2*)&z2r[(size_t)d * 32 + q * 2] = make_float2(zc0, zc1);
    float ps = zc0 * a_src2[q * 2] + zc1 * a_src2[q * 2 + 1];
    float pd = zc0 * a_dst2[q * 2] + zc1 * a_dst2[q * 2 + 1];
#pragma unroll
    for (int m = 1; m < 8; m <<= 1) {   // reduce over q (bits 0-2)
        ps += __shfl_xor(ps, m, 64);
        pd += __shfl_xor(pd, m, 64);
    }
    if (q == 0 && g == 0 && d < N) {    // as2/ad2 packed into the record
        z2r[(size_t)d * 32 + 16] = ps;
        z2r[(size_t)d * 32 + 17] = pd;
    }
}

// ---- KG2: 4 dsts/wave, 16 lanes/dst = 4 dims x 4-way edge split ---------
// lane = (dloc=lane>>4, g=(lane>>2)&3, c=lane&3). Post-loop shfl_xor(4,8)
// merges the 4 edge groups (reconverged). Packed z2r record: slice + as2
// in ONE 128B line (R19). Grid 3125 => ~full occupancy; chain ~4.3 iters.
__global__ void kg2(const int* __restrict__ deg, const int* __restrict__ csr,
                    const float* __restrict__ z2r, const float* __restrict__ b2,
                    float* __restrict__ out, int N) {
    __shared__ int s_idx[16][65];      // bank spread
    __shared__ int sdeg[16];
    int tid = threadIdx.x;
    int lane = tid & 63, wid = tid >> 6;
    int blk0 = blockIdx.x * 16;
    for (int idx = tid; idx < 1024; idx += 256) {   // coalesced CSR stage
        int dl = idx >> 6, sl = idx & 63;
        int dr = blk0 + dl; if (dr >= N) dr = N - 1;
        s_idx[dl][sl] = csr[(dr << 6) + sl];
    }
    if (tid < 16) {
        int dr = blk0 + tid; if (dr >= N) dr = N - 1;
        sdeg[tid] = min(deg[dr], 64);
    }
    __syncthreads();

    int dloc = lane >> 4, g = (lane >> 2) & 3, c = lane & 3;
    int dl16 = wid * 4 + dloc;
    int d = blk0 + dl16;
    int dc = d < N ? d : N - 1;
    int cnt = d < N ? sdeg[dl16] : 0;
    float adv = z2r[(size_t)dc * 32 + 17];
    float ax = 0.f, ay = 0.f, az = 0.f, aw = 0.f, dsum = 0.f;
#pragma unroll 2
    for (int j = g; j < cnt; j += 4) {
        int s = s_idx[dl16][j];                          // group broadcast
        float as2v = z2r[(size_t)s * 32 + 16];           // same 128B line
        float ev = as2v + adv;
        float w = __expf(LRELU(ev));
        float4 zv = *(const float4*)(z2r + (size_t)s * 32 + c * 4);
        ax += w * zv.x; ay += w * zv.y; az += w * zv.z; aw += w * zv.w;
        dsum += w;
    }
    // reconverged; merge the 4 edge groups (lane bits 2-3)
#pragma unroll
    for (int m = 4; m <= 8; m <<= 1) {
        ax += __shfl_xor(ax, m, 64); ay += __shfl_xor(ay, m, 64);
        az += __shfl_xor(az, m, 64); aw += __shfl_xor(aw, m, 64);
        dsum += __shfl_xor(dsum, m, 64);
    }
    if (g == 0 && d < N) {
        float inv = 1.f / dsum;
        float4 o = make_float4(ax * inv + b2[c * 4], ay * inv + b2[c * 4 + 1],
                               az * inv + b2[c * 4 + 2], aw * inv + b2[c * 4 + 3]);
        *(float4*)&out[(size_t)d * 16 + c * 4] = o;
    }
}

extern "C" void kernel_launch(void* const* d_in, const int* in_sizes, int n_in,
                              void* d_out, int out_size, void* d_ws, size_t ws_size,
                              hipStream_t stream) {
    const float* x      = (const float*)d_in[0];
    const int*   ei     = (const int*)d_in[1];
    const float* W1     = (const float*)d_in[2];
    const float* a_src1 = (const float*)d_in[3];
    const float* a_dst1 = (const float*)d_in[4];
    const float* b1     = (const float*)d_in[5];
    const float* W2     = (const float*)d_in[6];
    const float* a_src2 = (const float*)d_in[7];
    const float* a_dst2 = (const float*)d_in[8];
    const float* b2     = (const float*)d_in[9];
    float* out = (float*)d_out;

    const int N = in_sizes[0] / 128;   // 50000
    const int E = in_sizes[1] / 2;     // 850000
    const int* src = ei;
    const int* dst = ei + E;

    // Workspace (floats). z1h at 0; z2r at byte 8,000,000 (div 128 ✓).
    // pairs = 196*196*512 ints = 78.7MB. No memset: every cnts cell is
    // written unconditionally by its owning rank.
    float* ws = (float*)d_ws;
    size_t off = 0;
    __half* z1h = (__half*)(ws + off); off += (size_t)N * 32;  // N*64 halves
    float* ad1 = ws + off; off += (size_t)N * 8;
    float* z2r = ws + off; off += (size_t)N * 32;  // [0:16]=z2,[16]=as2,[17]=ad2
    int* csr = (int*)(ws + off); off += (size_t)N * 64;   // 64-slot buckets
    int* deg = (int*)(ws + off); off += (size_t)N;        // written by kB
    int* pairs = (int*)(ws + off); off += (size_t)NB * NB * CAP;
    int* cnts = (int*)(ws + off); off += (size_t)NB * NB;

    // 4 dispatches, no memset:
    kA<<<980, 256, 0, stream>>>(x, W1, a_dst1, src, dst, cnts, pairs,
                                z1h, ad1, N, E);
    kB<<<NB, 256, 0, stream>>>(cnts, pairs, deg, csr, N);
    kg1<<<(N + 15) / 16, 256, 0, stream>>>(deg, csr, a_src1, ad1, z1h, b1, W2,
                                           a_src2, a_dst2, z2r, N);
    kg2<<<(N + 15) / 16, 256, 0, stream>>>(deg, csr, z2r, b2, out, N);
}

// Round 14
// 163.053 us; speedup vs baseline: 1.3470x; 1.3470x over previous
//
#include <hip/hip_runtime.h>
#include <hip/hip_fp16.h>

// GAT, 2 layers, fp32 in/out. N=50000, E=850000 (incl. self-loops, deg>=1).
// R2: fp32 atomics -> CSR gather design. R8: bucketed CSR, fp16 z1.
// R10 FAILURE: cooperative launch silently no-ops — never use.
// R12 pad / R13 ILP / R16 transpose / R19 request-cut: NULL on gathers.
// R14 wt->L1: 173.6. R19 (as1 in-register, packed z2r, re-fused kA): 171.8.
// R20 FAILURE: 64-slot deterministic cells dropped edges (sequential
// self-loop tail -> 256/cell). R21: CAP=512 cells + kg occupancy
// restructure: total 219.6 BUT decomposition: kB 5.5->~88 (392-iter
// serial scan) while kg1+kg2 IMPROVED ~35us (~58 -> ~24) — first gather
// win in 6 tries; confirms rounds x chain-latency model.
// R22: KEEP R21 kg1/kg2 byte-identical; REVERT partition to R19's proven
// two-pass design (fused kA + kB 5.5us + bcnt memset). Best measured
// variant of every stage.
// R23/R24 (this round): RESUBMIT R22 unchanged — rounds 12 & 13 failed
// with "MI355X container failed twice" (broker/infra; kernel never ran;
// all components previously passed on-device in R19/R21 runs; workspace
// 31MB < R21's 95MB which ran). Third attempt; if infra fails again,
// vary the launch shape (fold memset into a kernel) to rule out
// pathological interaction.
// Predicted: kA ~25, kB ~5.5, kg1 ~16, kg2 ~10, fill 45, gaps ~25-30 =>
// total ~140-152. PRE-COMMIT: if >=165, REP kg1/kg2 next to verify their
// new singles.
// NOTE: 44-46us/256MiB fillBufferAligned = harness poison, fixed.
// No shfl inside divergent loops (R3) — only after reconvergence.
// Algebra: sum_e (exp/D)*z == (sum_e exp*z)/D — single pass per dst.

#define LRELU(v) ((v) > 0.f ? (v) : 0.2f * (v))

#define NB   196      // dst-range buckets = ceil(50000/256), bucket = dst>>8
#define BCAP 5120     // compact staging slots per bucket (mean 4352)

// ---- Kernel A: fused edge partition + tiled GEMM1 -----------------------
// blocks: b%5==4 -> partition rank b/5 (196 ranks); else GEMM tile
// (b/5)*4 + b%5 (784 slots, 782 used). Interleaving spreads both across
// all XCDs; GEMM VALU hides inside partition's memory stalls.
__global__ void __launch_bounds__(256, 4)
kA(const float* __restrict__ x, const float* __restrict__ W1,
   const float* __restrict__ a_dst1,
   const int* __restrict__ src, const int* __restrict__ dst,
   int* __restrict__ bcnt, int* __restrict__ pairs,
   __half* __restrict__ z1h, float* __restrict__ ad1, int N, int E) {
    __shared__ float xs[64][133];   // 133: stride 532 floats = 20 banks mod 32
    __shared__ float avs[64];       // a_dst1
    int b = blockIdx.x;
    int tid = threadIdx.x;
    bool is_part = ((b % 5) == 4);

    if (is_part) {
        // ---- partition path: histogram + reserve + staged scatter ----
        int* hist  = (int*)&xs[0][0];   // overlay on unused GEMM LDS
        int* base_ = hist + 256;
        int* cur   = hist + 512;
        int rank = b / 5;                       // 0..195
        if (tid < NB) hist[tid] = 0;
        __syncthreads();
        int chunk = (E + NB - 1) / NB;          // 4337
        int e0 = rank * chunk;
        int e1 = min(e0 + chunk, E);
        for (int e = e0 + tid; e < e1; e += 256)
            atomicAdd(&hist[dst[e] >> 8], 1);
        __syncthreads();
        if (tid < NB) {
            base_[tid] = atomicAdd(&bcnt[tid], hist[tid]);  // range reserve
            cur[tid] = 0;
        }
        __syncthreads();
        for (int e = e0 + tid; e < e1; e += 256) {
            int d = dst[e], s = src[e];
            int bk = d >> 8;
            int r = atomicAdd(&cur[bk], 1);     // LDS rank within block
            int idx = base_[bk] + r;
            if (idx < BCAP) pairs[bk * BCAP + idx] = (s << 8) | (d & 255);
        }
        return;
    }

    // ---- GEMM path: 64 nodes x 64 cols, 4x4 register tile per thread ----
    int tile = (b / 5) * 4 + (b % 5);
    if (tile >= 782) return;
    int n0 = tile * 64;
    for (int idx = tid; idx < 2048; idx += 256) {
        int r = idx >> 5, q = idx & 31;
        int n = n0 + r; if (n >= N) n = N - 1;  // clamp; dup rows unused
        float4 v = ((const float4*)(x + (size_t)n * 128))[q];
        *(float4*)&xs[r][q * 4] = v;
    }
    if (tid < 64) avs[tid] = a_dst1[tid];
    __syncthreads();

    int rg = tid >> 4, cg2 = tid & 15;
    int xr = rg * 4;
    // W1 row-major [128][64]: thread reads float4 W1[k][cg2*4..+3] — one
    // 256B row per wave, 4x lane-duplicated -> L1 broadcast (R14).
    const float4* wb = (const float4*)W1 + cg2;   // row k = wb[k*16]
    float acc[4][4] = {};
    float4 xv[4], wl[4];
#pragma unroll
    for (int i = 0; i < 4; ++i) xv[i] = *(const float4*)&xs[xr + i][0];
#pragma unroll
    for (int kk = 0; kk < 4; ++kk) wl[kk] = wb[kk * 16];
#pragma unroll 2
    for (int k4 = 0; k4 < 32; ++k4) {
        float4 xn[4], wn[4];
        int kn = (k4 + 1) & 31;
#pragma unroll
        for (int i = 0; i < 4; ++i) xn[i] = *(const float4*)&xs[xr + i][kn * 4];
#pragma unroll
        for (int kk = 0; kk < 4; ++kk) wn[kk] = wb[(kn * 4 + kk) * 16];
#pragma unroll
        for (int i = 0; i < 4; ++i) {
            acc[i][0] += xv[i].x * wl[0].x; acc[i][1] += xv[i].x * wl[0].y;
            acc[i][2] += xv[i].x * wl[0].z; acc[i][3] += xv[i].x * wl[0].w;
            acc[i][0] += xv[i].y * wl[1].x; acc[i][1] += xv[i].y * wl[1].y;
            acc[i][2] += xv[i].y * wl[1].z; acc[i][3] += xv[i].y * wl[1].w;
            acc[i][0] += xv[i].z * wl[2].x; acc[i][1] += xv[i].z * wl[2].y;
            acc[i][2] += xv[i].z * wl[2].z; acc[i][3] += xv[i].z * wl[2].w;
            acc[i][0] += xv[i].w * wl[3].x; acc[i][1] += xv[i].w * wl[3].y;
            acc[i][2] += xv[i].w * wl[3].z; acc[i][3] += xv[i].w * wl[3].w;
        }
#pragma unroll
        for (int i = 0; i < 4; ++i) { xv[i] = xn[i]; wl[i] = wn[i]; }
    }
    int h = cg2 >> 1, db = (cg2 & 1) * 4;
    float pad_[4];
#pragma unroll
    for (int i = 0; i < 4; ++i) {
        float dd = 0.f;
#pragma unroll
        for (int j = 0; j < 4; ++j) dd += acc[i][j] * avs[h * 8 + db + j];
        pad_[i] = dd;
    }
#pragma unroll
    for (int i = 0; i < 4; ++i)    // pair-reduce cg even/odd (full exec)
        pad_[i] += __shfl_xor(pad_[i], 1, 64);
#pragma unroll
    for (int i = 0; i < 4; ++i) {
        int n = n0 + rg * 4 + i;
        if (n < N) {
            union { __half2 h2[2]; uint2 u; } pk;
            pk.h2[0] = __floats2half2_rn(acc[i][0], acc[i][1]);
            pk.h2[1] = __floats2half2_rn(acc[i][2], acc[i][3]);
            *(uint2*)&z1h[(size_t)n * 64 + cg2 * 4] = pk.u;   // 8B aligned
            if ((cg2 & 1) == 0) ad1[(size_t)n * 8 + h] = pad_[i];
        }
    }
}

// ---- Kernel B: per-bucket CSR build (R19 form, measured ~5.5us) ---------
// block b owns bucket b: compact staged entries read coalesced; rank via
// LDS atomicAdd; scatter csr inside the single-writer 64KB region; write
// deg directly.
__global__ void kB(const int* __restrict__ bcnt, const int* __restrict__ pairs,
                   int* __restrict__ deg, int* __restrict__ csr, int N) {
    __shared__ int cur[256];
    int b = blockIdx.x;
    int tid = threadIdx.x;
    cur[tid] = 0;
    __syncthreads();
    int nb = min(bcnt[b], BCAP);
    const int* p = pairs + b * BCAP;
    for (int i = tid; i < nb; i += 256) {
        int v = p[i];
        int off = v & 255, s = v >> 8;
        int r = atomicAdd(&cur[off], 1);
        if (r < 64) csr[(((b << 8) + off) << 6) + r] = s;
    }
    __syncthreads();
    int d = (b << 8) + tid;
    if (d < N) deg[d] = cur[tid];
}

// ---- KG1: 4 dsts/wave, 16 lanes/dst = 8 heads x 2-way edge split --------
// (R21, proven) lane = (dloc=lane>>4, g=(lane>>3)&1, q=lane&7). Post-loop
// shfl_xor(8) merges halves (reconverged — R3-safe). as1 in-register
// (R19); packed z2r epilogue (R19); block-cooperative staging (R20).
// Grid 3125 => ~full occupancy; chain ~8.5 iters.
__global__ void kg1(const int* __restrict__ deg, const int* __restrict__ csr,
                    const float* __restrict__ a_src1, const float* __restrict__ ad1,
                    const __half* __restrict__ z1h, const float* __restrict__ b1,
                    const float* __restrict__ W2, const float* __restrict__ a_src2,
                    const float* __restrict__ a_dst2,
                    float* __restrict__ z2r, int N) {
    __shared__ int s_idx[16][65];      // 65: bank spread
    __shared__ int sdeg[16];
    __shared__ float hs[4][4][68];     // 68: dloc*4 bank offset, 16B rows
    __shared__ float ws2[64][18];      // 18: 8B-aligned float2, spread banks
    int tid = threadIdx.x;
    int lane = tid & 63, wid = tid >> 6;
    int blk0 = blockIdx.x * 16;
    for (int i = tid; i < 1024; i += 256) ws2[i >> 4][i & 15] = W2[i];
    for (int idx = tid; idx < 1024; idx += 256) {   // coalesced CSR stage
        int dl = idx >> 6, sl = idx & 63;
        int dr = blk0 + dl; if (dr >= N) dr = N - 1;
        s_idx[dl][sl] = csr[(dr << 6) + sl];
    }
    if (tid < 16) {
        int dr = blk0 + tid; if (dr >= N) dr = N - 1;
        sdeg[tid] = min(deg[dr], 64);
    }
    __syncthreads();

    int dloc = lane >> 4, g = (lane >> 3) & 1, q = lane & 7;
    int dl16 = wid * 4 + dloc;
    int d = blk0 + dl16;
    int dc = d < N ? d : N - 1;
    int cnt = d < N ? sdeg[dl16] : 0;
    float adv = ad1[(size_t)dc * 8 + q];
    float4 asA = *(const float4*)(a_src1 + q * 8);      // a_src1[q][0..3]
    float4 asB = *(const float4*)(a_src1 + q * 8 + 4);  // a_src1[q][4..7]
    float a0 = 0.f, a1 = 0.f, a2 = 0.f, a3 = 0.f;
    float a4 = 0.f, a5 = 0.f, a6 = 0.f, a7 = 0.f, dsum = 0.f;
#pragma unroll 2
    for (int j = g; j < cnt; j += 2) {
        int s = s_idx[dl16][j];                          // group broadcast
        float4 raw = *(const float4*)(z1h + (size_t)s * 64 + q * 8);  // 8 halves
        const __half2* hp = (const __half2*)&raw;
        float2 f0 = __half22float2(hp[0]), f1 = __half22float2(hp[1]);
        float2 f2 = __half22float2(hp[2]), f3 = __half22float2(hp[3]);
        float av = f0.x * asA.x + f0.y * asA.y + f1.x * asA.z + f1.y * asA.w
                 + f2.x * asB.x + f2.y * asB.y + f3.x * asB.z + f3.y * asB.w;
        float ev = av + adv;
        float w = __expf(LRELU(ev));
        a0 += w * f0.x; a1 += w * f0.y; a2 += w * f1.x; a3 += w * f1.y;
        a4 += w * f2.x; a5 += w * f2.y; a6 += w * f3.x; a7 += w * f3.y;
        dsum += w;
    }
    // reconverged; merge the two edge halves (lanes differ in bit 3)
    a0 += __shfl_xor(a0, 8, 64); a1 += __shfl_xor(a1, 8, 64);
    a2 += __shfl_xor(a2, 8, 64); a3 += __shfl_xor(a3, 8, 64);
    a4 += __shfl_xor(a4, 8, 64); a5 += __shfl_xor(a5, 8, 64);
    a6 += __shfl_xor(a6, 8, 64); a7 += __shfl_xor(a7, 8, 64);
    dsum += __shfl_xor(dsum, 8, 64);
    float inv = cnt ? 1.f / dsum : 0.f;
    float4 bv0 = *(const float4*)(b1 + q * 8);
    float4 bv1 = *(const float4*)(b1 + q * 8 + 4);
    float hv[8] = {a0 * inv + bv0.x, a1 * inv + bv0.y,
                   a2 * inv + bv0.z, a3 * inv + bv0.w,
                   a4 * inv + bv1.x, a5 * inv + bv1.y,
                   a6 * inv + bv1.z, a7 * inv + bv1.w};
#pragma unroll
    for (int i = 0; i < 8; ++i) hv[i] = hv[i] > 0.f ? hv[i] : expm1f(hv[i]);
    if (g == 0) {
        *(float4*)&hs[wid][dloc][q * 8]     = make_float4(hv[0], hv[1], hv[2], hv[3]);
        *(float4*)&hs[wid][dloc][q * 8 + 4] = make_float4(hv[4], hv[5], hv[6], hv[7]);
    }
    // hs: same-wave RAW -> no barrier. GEMM2: lane = (dst dloc, colpair q),
    // both g halves compute identical zc (redundant, harmless).
    float zc0 = 0.f, zc1 = 0.f;
#pragma unroll
    for (int k4 = 0; k4 < 16; ++k4) {
        float4 hh = *(const float4*)&hs[wid][dloc][k4 * 4];
        float2 w0 = *(const float2*)&ws2[k4 * 4 + 0][q * 2];
        float2 w1 = *(const float2*)&ws2[k4 * 4 + 1][q * 2];
        float2 w2 = *(const float2*)&ws2[k4 * 4 + 2][q * 2];
        float2 w3 = *(const float2*)&ws2[k4 * 4 + 3][q * 2];
        zc0 += hh.x * w0.x; zc1 += hh.x * w0.y;
        zc0 += hh.y * w1.x; zc1 += hh.y * w1.y;
        zc0 += hh.z * w2.x; zc1 += hh.z * w2.y;
        zc0 += hh.w * w3.x; zc1 += hh.w * w3.y;
    }
    if (g == 0 && d < N)
        *(float2*)&z2r[(size_t)d * 32 + q * 2] = make_float2(zc0, zc1);
    float ps = zc0 * a_src2[q * 2] + zc1 * a_src2[q * 2 + 1];
    float pd = zc0 * a_dst2[q * 2] + zc1 * a_dst2[q * 2 + 1];
#pragma unroll
    for (int m = 1; m < 8; m <<= 1) {   // reduce over q (bits 0-2)
        ps += __shfl_xor(ps, m, 64);
        pd += __shfl_xor(pd, m, 64);
    }
    if (q == 0 && g == 0 && d < N) {    // as2/ad2 packed into the record
        z2r[(size_t)d * 32 + 16] = ps;
        z2r[(size_t)d * 32 + 17] = pd;
    }
}

// ---- KG2: 4 dsts/wave, 16 lanes/dst = 4 dims x 4-way edge split ---------
// (R21, proven) lane = (dloc, g=(lane>>2)&3, c=lane&3). Post-loop
// shfl_xor(4,8) merges the 4 edge groups (reconverged). Packed z2r: slice
// + as2 in ONE 128B line (R19). Grid 3125; chain ~4.3 iters.
__global__ void kg2(const int* __restrict__ deg, const int* __restrict__ csr,
                    const float* __restrict__ z2r, const float* __restrict__ b2,
                    float* __restrict__ out, int N) {
    __shared__ int s_idx[16][65];      // bank spread
    __shared__ int sdeg[16];
    int tid = threadIdx.x;
    int lane = tid & 63, wid = tid >> 6;
    int blk0 = blockIdx.x * 16;
    for (int idx = tid; idx < 1024; idx += 256) {   // coalesced CSR stage
        int dl = idx >> 6, sl = idx & 63;
        int dr = blk0 + dl; if (dr >= N) dr = N - 1;
        s_idx[dl][sl] = csr[(dr << 6) + sl];
    }
    if (tid < 16) {
        int dr = blk0 + tid; if (dr >= N) dr = N - 1;
        sdeg[tid] = min(deg[dr], 64);
    }
    __syncthreads();

    int dloc = lane >> 4, g = (lane >> 2) & 3, c = lane & 3;
    int dl16 = wid * 4 + dloc;
    int d = blk0 + dl16;
    int dc = d < N ? d : N - 1;
    int cnt = d < N ? sdeg[dl16] : 0;
    float adv = z2r[(size_t)dc * 32 + 17];
    float ax = 0.f, ay = 0.f, az = 0.f, aw = 0.f, dsum = 0.f;
#pragma unroll 2
    for (int j = g; j < cnt; j += 4) {
        int s = s_idx[dl16][j];                          // group broadcast
        float as2v = z2r[(size_t)s * 32 + 16];           // same 128B line
        float ev = as2v + adv;
        float w = __expf(LRELU(ev));
        float4 zv = *(const float4*)(z2r + (size_t)s * 32 + c * 4);
        ax += w * zv.x; ay += w * zv.y; az += w * zv.z; aw += w * zv.w;
        dsum += w;
    }
    // reconverged; merge the 4 edge groups (lane bits 2-3)
#pragma unroll
    for (int m = 4; m <= 8; m <<= 1) {
        ax += __shfl_xor(ax, m, 64); ay += __shfl_xor(ay, m, 64);
        az += __shfl_xor(az, m, 64); aw += __shfl_xor(aw, m, 64);
        dsum += __shfl_xor(dsum, m, 64);
    }
    if (g == 0 && d < N) {
        float inv = 1.f / dsum;
        float4 o = make_float4(ax * inv + b2[c * 4], ay * inv + b2[c * 4 + 1],
                               az * inv + b2[c * 4 + 2], aw * inv + b2[c * 4 + 3]);
        *(float4*)&out[(size_t)d * 16 + c * 4] = o;
    }
}

extern "C" void kernel_launch(void* const* d_in, const int* in_sizes, int n_in,
                              void* d_out, int out_size, void* d_ws, size_t ws_size,
                              hipStream_t stream) {
    const float* x      = (const float*)d_in[0];
    const int*   ei     = (const int*)d_in[1];
    const float* W1     = (const float*)d_in[2];
    const float* a_src1 = (const float*)d_in[3];
    const float* a_dst1 = (const float*)d_in[4];
    const float* b1     = (const float*)d_in[5];
    const float* W2     = (const float*)d_in[6];
    const float* a_src2 = (const float*)d_in[7];
    const float* a_dst2 = (const float*)d_in[8];
    const float* b2     = (const float*)d_in[9];
    float* out = (float*)d_out;

    const int N = in_sizes[0] / 128;   // 50000
    const int E = in_sizes[1] / 2;     // 850000
    const int* src = ei;
    const int* dst = ei + E;

    // Workspace (floats). z1h at 0; z2r at byte 8,000,000 (div 128 ✓) —
    // packed 32-float records [0:16]=z2,[16]=as2,[17]=ad2.
    float* ws = (float*)d_ws;
    size_t off = 0;
    __half* z1h = (__half*)(ws + off); off += (size_t)N * 32;  // N*64 halves
    float* ad1 = ws + off; off += (size_t)N * 8;
    float* z2r = ws + off; off += (size_t)N * 32;
    int* csr = (int*)(ws + off); off += (size_t)N * 64;   // 64-slot buckets
    int* deg = (int*)(ws + off); off += (size_t)N;        // written by kB
    int* pairs = (int*)(ws + off); off += (size_t)NB * BCAP;  // compact staging
    int* bcnt = (int*)(ws + off); off += NB;              // memset region

    hipMemsetAsync(bcnt, 0, (size_t)NB * sizeof(int), stream);

    // kA: 784 GEMM tile slots (782 used) + 196 partition ranks, interleaved
    kA<<<980, 256, 0, stream>>>(x, W1, a_dst1, src, dst, bcnt, pairs,
                                z1h, ad1, N, E);
    kB<<<NB, 256, 0, stream>>>(bcnt, pairs, deg, csr, N);
    kg1<<<(N + 15) / 16, 256, 0, stream>>>(deg, csr, a_src1, ad1, z1h, b1, W2,
                                           a_src2, a_dst2, z2r, N);
    kg2<<<(N + 15) / 16, 256, 0, stream>>>(deg, csr, z2r, b2, out, N);
}

// Round 15
// 157.741 us; speedup vs baseline: 1.3923x; 1.0337x over previous
//
#include <hip/hip_runtime.h>
#include <hip/hip_fp16.h>

// GAT, 2 layers, fp32 in/out. N=50000, E=850000 (incl. self-loops, deg>=1).
// R2: fp32 atomics -> CSR gather design. R8: bucketed CSR, fp16 z1.
// R10 FAILURE: cooperative launch silently no-ops — never use.
// R12 pad / R13 ILP / R16 transpose / R19 request-cut: NULL on gathers.
// R14 wt->L1: 173.6. R19 (as1 in-register, packed z2r): 171.8.
// R20 FAILURE: 64-slot cells dropped edges (sequential self-loop tail).
// R21: kg occupancy restructure (4 dst/wave, 16 lanes/dst) = first gather
// win; kB CAP-scan regression. R22: recombined best-of-each: 163.05 (best).
// R25 (this round): kA GEMM1 -> MFMA. R18 measured the f32-vector GEMM at
// 21.7us (VALUBusy 32%, FMA floor 5.6us); MfmaUtil has been 0.0 all
// session. v_mfma_f32_16x16x32_f16: per 64x64 tile stage x,W1^T as f16 in
// LDS [64][136] (stride 68 dwords = 4 banks -> 2-way/free b128 reads);
// wave owns 16 rows: 4 col-subtiles x 4 K-steps = 16 MFMA. C/D layout
// col=lane&15,row=(lane>>4)*4+reg (HW-verified m89, dtype-independent);
// A/B standard CDNA map (row/col=lane&15, k=(lane>>4)*8+j). ad1 reduced
// post-loop over lane bits 0-2 (full-exec). f16 inputs add <=~1e-2 error
// on top of existing z1h fp16 rounding (0.0156 now, 0.0606 threshold).
// Predicted: kA ~25 -> 13-16, total -> ~150-156, absmax <= 0.035.
// PRE-COMMIT: absmax blowup => A/B fragment layout wrong -> swap next;
// total flat + absmax ok => kA wasn't 25us -> REP kA next.
// NOTE: 44-46us/256MiB fillBufferAligned = harness poison, fixed.
// No shfl inside divergent loops (R3) — only after reconvergence.
// Algebra: sum_e (exp/D)*z == (sum_e exp*z)/D — single pass per dst.

#define LRELU(v) ((v) > 0.f ? (v) : 0.2f * (v))

#define NB   196      // dst-range buckets = ceil(50000/256), bucket = dst>>8
#define BCAP 5120     // compact staging slots per bucket (mean 4352)

typedef _Float16 f16x8 __attribute__((ext_vector_type(8)));
typedef float f32x4 __attribute__((ext_vector_type(4)));

// ---- Kernel A: fused edge partition + MFMA GEMM1 ------------------------
// blocks: b%5==4 -> partition rank b/5 (196 ranks); else GEMM tile
// (b/5)*4 + b%5 (784 slots, 782 used). Interleaving spreads both across
// all XCDs; GEMM (now matrix-pipe) hides inside partition's memory stalls.
__global__ void __launch_bounds__(256, 4)
kA(const float* __restrict__ x, const float* __restrict__ W1,
   const float* __restrict__ a_dst1,
   const int* __restrict__ src, const int* __restrict__ dst,
   int* __restrict__ bcnt, int* __restrict__ pairs,
   __half* __restrict__ z1h, float* __restrict__ ad1, int N, int E) {
    __shared__ __half xsh[64][136];  // 136: stride 272B = 68 dw = 4 banks/row
    __shared__ __half wtT[64][136];  // W1 transposed: wtT[col][k]
    __shared__ float avs[64];        // a_dst1
    int b = blockIdx.x;
    int tid = threadIdx.x;
    bool is_part = ((b % 5) == 4);

    if (is_part) {
        // ---- partition path: histogram + reserve + staged scatter ----
        int* hist  = (int*)&xsh[0][0];  // overlay on unused GEMM LDS
        int* base_ = hist + 256;
        int* cur   = hist + 512;
        int rank = b / 5;                       // 0..195
        if (tid < NB) hist[tid] = 0;
        __syncthreads();
        int chunk = (E + NB - 1) / NB;          // 4337
        int e0 = rank * chunk;
        int e1 = min(e0 + chunk, E);
        for (int e = e0 + tid; e < e1; e += 256)
            atomicAdd(&hist[dst[e] >> 8], 1);
        __syncthreads();
        if (tid < NB) {
            base_[tid] = atomicAdd(&bcnt[tid], hist[tid]);  // range reserve
            cur[tid] = 0;
        }
        __syncthreads();
        for (int e = e0 + tid; e < e1; e += 256) {
            int d = dst[e], s = src[e];
            int bk = d >> 8;
            int r = atomicAdd(&cur[bk], 1);     // LDS rank within block
            int idx = base_[bk] + r;
            if (idx < BCAP) pairs[bk * BCAP + idx] = (s << 8) | (d & 255);
        }
        return;
    }

    // ---- GEMM path: 64 nodes x 64 cols, MFMA f16, fp32 accum ----
    int tile = (b / 5) * 4 + (b % 5);
    if (tile >= 782) return;
    int n0 = tile * 64;
    // stage x-tile as f16 (float4 read -> 4x f16 packed write, 8B aligned)
    for (int idx = tid; idx < 2048; idx += 256) {
        int r = idx >> 5, q = idx & 31;
        int n = n0 + r; if (n >= N) n = N - 1;  // clamp; dup rows unused
        float4 v = ((const float4*)(x + (size_t)n * 128))[q];
        union { __half2 h2[2]; uint2 u; } pk;
        pk.h2[0] = __floats2half2_rn(v.x, v.y);
        pk.h2[1] = __floats2half2_rn(v.z, v.w);
        *(uint2*)&xsh[r][q * 4] = pk.u;
    }
    // stage W1^T as f16: k-pair packed (one __half2 = W1[2k][c],W1[2k+1][c])
    for (int idx = tid; idx < 1024; idx += 256) {
        int kp = idx >> 4, cq = idx & 15;       // kp 0..63 k-pairs, cq col-quad
        float4 va = ((const float4*)(W1 + (size_t)(kp * 2) * 64))[cq];
        float4 vb = ((const float4*)(W1 + (size_t)(kp * 2 + 1) * 64))[cq];
        int c = cq * 4;
        *(__half2*)&wtT[c + 0][kp * 2] = __floats2half2_rn(va.x, vb.x);
        *(__half2*)&wtT[c + 1][kp * 2] = __floats2half2_rn(va.y, vb.y);
        *(__half2*)&wtT[c + 2][kp * 2] = __floats2half2_rn(va.z, vb.z);
        *(__half2*)&wtT[c + 3][kp * 2] = __floats2half2_rn(va.w, vb.w);
    }
    if (tid < 64) avs[tid] = a_dst1[tid];
    __syncthreads();

    int lane = tid & 63, wv = tid >> 6;
    int rsub = lane & 15, kg = lane >> 4;       // A row / B col = rsub; k-group
    f32x4 acc0 = {0.f, 0.f, 0.f, 0.f}, acc1 = {0.f, 0.f, 0.f, 0.f};
    f32x4 acc2 = {0.f, 0.f, 0.f, 0.f}, acc3 = {0.f, 0.f, 0.f, 0.f};
#pragma unroll
    for (int k0 = 0; k0 < 128; k0 += 32) {
        f16x8 av = *(const f16x8*)&xsh[wv * 16 + rsub][k0 + kg * 8];
        f16x8 b0 = *(const f16x8*)&wtT[rsub][k0 + kg * 8];
        f16x8 b1 = *(const f16x8*)&wtT[16 + rsub][k0 + kg * 8];
        f16x8 b2 = *(const f16x8*)&wtT[32 + rsub][k0 + kg * 8];
        f16x8 b3 = *(const f16x8*)&wtT[48 + rsub][k0 + kg * 8];
        acc0 = __builtin_amdgcn_mfma_f32_16x16x32_f16(av, b0, acc0, 0, 0, 0);
        acc1 = __builtin_amdgcn_mfma_f32_16x16x32_f16(av, b1, acc1, 0, 0, 0);
        acc2 = __builtin_amdgcn_mfma_f32_16x16x32_f16(av, b2, acc2, 0, 0, 0);
        acc3 = __builtin_amdgcn_mfma_f32_16x16x32_f16(av, b3, acc3, 0, 0, 0);
    }
    // D layout: lane holds D[row=kg*4+reg][col=ct*16+rsub] in acc{ct}[reg].
#pragma unroll
    for (int reg = 0; reg < 4; ++reg) {
        int n = n0 + wv * 16 + kg * 4 + reg;
        // z1h: 4 scalar f16 stores/reg (16 lanes -> 32B contiguous each)
        if (n < N) {
            __half* zp = z1h + (size_t)n * 64 + rsub;
            zp[0]  = __float2half_rn(acc0[reg]);
            zp[16] = __float2half_rn(acc1[reg]);
            zp[32] = __float2half_rn(acc2[reg]);
            zp[48] = __float2half_rn(acc3[reg]);
        }
        // ad1: head h = ct*2 + (rsub>>3); reduce over lane bits 0-2
        // (full exec, post-MFMA — R3-safe)
        float v0 = acc0[reg] * avs[rsub];
        float v1 = acc1[reg] * avs[16 + rsub];
        float v2 = acc2[reg] * avs[32 + rsub];
        float v3 = acc3[reg] * avs[48 + rsub];
        v0 += __shfl_xor(v0, 1, 64); v0 += __shfl_xor(v0, 2, 64); v0 += __shfl_xor(v0, 4, 64);
        v1 += __shfl_xor(v1, 1, 64); v1 += __shfl_xor(v1, 2, 64); v1 += __shfl_xor(v1, 4, 64);
        v2 += __shfl_xor(v2, 1, 64); v2 += __shfl_xor(v2, 2, 64); v2 += __shfl_xor(v2, 4, 64);
        v3 += __shfl_xor(v3, 1, 64); v3 += __shfl_xor(v3, 2, 64); v3 += __shfl_xor(v3, 4, 64);
        if ((rsub & 7) == 0 && n < N) {
            int hi = rsub >> 3;                  // 0 or 1
            float* ap = ad1 + (size_t)n * 8 + hi;
            ap[0] = v0; ap[2] = v1; ap[4] = v2; ap[6] = v3;
        }
    }
}

// ---- Kernel B: per-bucket CSR build (R19 form, measured ~5.5us) ---------
// block b owns bucket b: compact staged entries read coalesced; rank via
// LDS atomicAdd; scatter csr inside the single-writer 64KB region; write
// deg directly.
__global__ void kB(const int* __restrict__ bcnt, const int* __restrict__ pairs,
                   int* __restrict__ deg, int* __restrict__ csr, int N) {
    __shared__ int cur[256];
    int b = blockIdx.x;
    int tid = threadIdx.x;
    cur[tid] = 0;
    __syncthreads();
    int nb = min(bcnt[b], BCAP);
    const int* p = pairs + b * BCAP;
    for (int i = tid; i < nb; i += 256) {
        int v = p[i];
        int off = v & 255, s = v >> 8;
        int r = atomicAdd(&cur[off], 1);
        if (r < 64) csr[(((b << 8) + off) << 6) + r] = s;
    }
    __syncthreads();
    int d = (b << 8) + tid;
    if (d < N) deg[d] = cur[tid];
}

// ---- KG1: 4 dsts/wave, 16 lanes/dst = 8 heads x 2-way edge split --------
// (R21, proven) lane = (dloc=lane>>4, g=(lane>>3)&1, q=lane&7). Post-loop
// shfl_xor(8) merges halves (reconverged — R3-safe). as1 in-register
// (R19); packed z2r epilogue (R19); block-cooperative staging (R20).
// Grid 3125 => ~full occupancy; chain ~8.5 iters.
__global__ void kg1(const int* __restrict__ deg, const int* __restrict__ csr,
                    const float* __restrict__ a_src1, const float* __restrict__ ad1,
                    const __half* __restrict__ z1h, const float* __restrict__ b1,
                    const float* __restrict__ W2, const float* __restrict__ a_src2,
                    const float* __restrict__ a_dst2,
                    float* __restrict__ z2r, int N) {
    __shared__ int s_idx[16][65];      // 65: bank spread
    __shared__ int sdeg[16];
    __shared__ float hs[4][4][68];     // 68: dloc*4 bank offset, 16B rows
    __shared__ float ws2[64][18];      // 18: 8B-aligned float2, spread banks
    int tid = threadIdx.x;
    int lane = tid & 63, wid = tid >> 6;
    int blk0 = blockIdx.x * 16;
    for (int i = tid; i < 1024; i += 256) ws2[i >> 4][i & 15] = W2[i];
    for (int idx = tid; idx < 1024; idx += 256) {   // coalesced CSR stage
        int dl = idx >> 6, sl = idx & 63;
        int dr = blk0 + dl; if (dr >= N) dr = N - 1;
        s_idx[dl][sl] = csr[(dr << 6) + sl];
    }
    if (tid < 16) {
        int dr = blk0 + tid; if (dr >= N) dr = N - 1;
        sdeg[tid] = min(deg[dr], 64);
    }
    __syncthreads();

    int dloc = lane >> 4, g = (lane >> 3) & 1, q = lane & 7;
    int dl16 = wid * 4 + dloc;
    int d = blk0 + dl16;
    int dc = d < N ? d : N - 1;
    int cnt = d < N ? sdeg[dl16] : 0;
    float adv = ad1[(size_t)dc * 8 + q];
    float4 asA = *(const float4*)(a_src1 + q * 8);      // a_src1[q][0..3]
    float4 asB = *(const float4*)(a_src1 + q * 8 + 4);  // a_src1[q][4..7]
    float a0 = 0.f, a1 = 0.f, a2 = 0.f, a3 = 0.f;
    float a4 = 0.f, a5 = 0.f, a6 = 0.f, a7 = 0.f, dsum = 0.f;
#pragma unroll 2
    for (int j = g; j < cnt; j += 2) {
        int s = s_idx[dl16][j];                          // group broadcast
        float4 raw = *(const float4*)(z1h + (size_t)s * 64 + q * 8);  // 8 halves
        const __half2* hp = (const __half2*)&raw;
        float2 f0 = __half22float2(hp[0]), f1 = __half22float2(hp[1]);
        float2 f2 = __half22float2(hp[2]), f3 = __half22float2(hp[3]);
        float av = f0.x * asA.x + f0.y * asA.y + f1.x * asA.z + f1.y * asA.w
                 + f2.x * asB.x + f2.y * asB.y + f3.x * asB.z + f3.y * asB.w;
        float ev = av + adv;
        float w = __expf(LRELU(ev));
        a0 += w * f0.x; a1 += w * f0.y; a2 += w * f1.x; a3 += w * f1.y;
        a4 += w * f2.x; a5 += w * f2.y; a6 += w * f3.x; a7 += w * f3.y;
        dsum += w;
    }
    // reconverged; merge the two edge halves (lanes differ in bit 3)
    a0 += __shfl_xor(a0, 8, 64); a1 += __shfl_xor(a1, 8, 64);
    a2 += __shfl_xor(a2, 8, 64); a3 += __shfl_xor(a3, 8, 64);
    a4 += __shfl_xor(a4, 8, 64); a5 += __shfl_xor(a5, 8, 64);
    a6 += __shfl_xor(a6, 8, 64); a7 += __shfl_xor(a7, 8, 64);
    dsum += __shfl_xor(dsum, 8, 64);
    float inv = cnt ? 1.f / dsum : 0.f;
    float4 bv0 = *(const float4*)(b1 + q * 8);
    float4 bv1 = *(const float4*)(b1 + q * 8 + 4);
    float hv[8] = {a0 * inv + bv0.x, a1 * inv + bv0.y,
                   a2 * inv + bv0.z, a3 * inv + bv0.w,
                   a4 * inv + bv1.x, a5 * inv + bv1.y,
                   a6 * inv + bv1.z, a7 * inv + bv1.w};
#pragma unroll
    for (int i = 0; i < 8; ++i) hv[i] = hv[i] > 0.f ? hv[i] : expm1f(hv[i]);
    if (g == 0) {
        *(float4*)&hs[wid][dloc][q * 8]     = make_float4(hv[0], hv[1], hv[2], hv[3]);
        *(float4*)&hs[wid][dloc][q * 8 + 4] = make_float4(hv[4], hv[5], hv[6], hv[7]);
    }
    // hs: same-wave RAW -> no barrier. GEMM2: lane = (dst dloc, colpair q),
    // both g halves compute identical zc (redundant, harmless).
    float zc0 = 0.f, zc1 = 0.f;
#pragma unroll
    for (int k4 = 0; k4 < 16; ++k4) {
        float4 hh = *(const float4*)&hs[wid][dloc][k4 * 4];
        float2 w0 = *(const float2*)&ws2[k4 * 4 + 0][q * 2];
        float2 w1 = *(const float2*)&ws2[k4 * 4 + 1][q * 2];
        float2 w2 = *(const float2*)&ws2[k4 * 4 + 2][q * 2];
        float2 w3 = *(const float2*)&ws2[k4 * 4 + 3][q * 2];
        zc0 += hh.x * w0.x; zc1 += hh.x * w0.y;
        zc0 += hh.y * w1.x; zc1 += hh.y * w1.y;
        zc0 += hh.z * w2.x; zc1 += hh.z * w2.y;
        zc0 += hh.w * w3.x; zc1 += hh.w * w3.y;
    }
    if (g == 0 && d < N)
        *(float2*)&z2r[(size_t)d * 32 + q * 2] = make_float2(zc0, zc1);
    float ps = zc0 * a_src2[q * 2] + zc1 * a_src2[q * 2 + 1];
    float pd = zc0 * a_dst2[q * 2] + zc1 * a_dst2[q * 2 + 1];
#pragma unroll
    for (int m = 1; m < 8; m <<= 1) {   // reduce over q (bits 0-2)
        ps += __shfl_xor(ps, m, 64);
        pd += __shfl_xor(pd, m, 64);
    }
    if (q == 0 && g == 0 && d < N) {    // as2/ad2 packed into the record
        z2r[(size_t)d * 32 + 16] = ps;
        z2r[(size_t)d * 32 + 17] = pd;
    }
}

// ---- KG2: 4 dsts/wave, 16 lanes/dst = 4 dims x 4-way edge split ---------
// (R21, proven) lane = (dloc, g=(lane>>2)&3, c=lane&3). Post-loop
// shfl_xor(4,8) merges the 4 edge groups (reconverged). Packed z2r: slice
// + as2 in ONE 128B line (R19). Grid 3125; chain ~4.3 iters.
__global__ void kg2(const int* __restrict__ deg, const int* __restrict__ csr,
                    const float* __restrict__ z2r, const float* __restrict__ b2,
                    float* __restrict__ out, int N) {
    __shared__ int s_idx[16][65];      // bank spread
    __shared__ int sdeg[16];
    int tid = threadIdx.x;
    int lane = tid & 63, wid = tid >> 6;
    int blk0 = blockIdx.x * 16;
    for (int idx = tid; idx < 1024; idx += 256) {   // coalesced CSR stage
        int dl = idx >> 6, sl = idx & 63;
        int dr = blk0 + dl; if (dr >= N) dr = N - 1;
        s_idx[dl][sl] = csr[(dr << 6) + sl];
    }
    if (tid < 16) {
        int dr = blk0 + tid; if (dr >= N) dr = N - 1;
        sdeg[tid] = min(deg[dr], 64);
    }
    __syncthreads();

    int dloc = lane >> 4, g = (lane >> 2) & 3, c = lane & 3;
    int dl16 = wid * 4 + dloc;
    int d = blk0 + dl16;
    int dc = d < N ? d : N - 1;
    int cnt = d < N ? sdeg[dl16] : 0;
    float adv = z2r[(size_t)dc * 32 + 17];
    float ax = 0.f, ay = 0.f, az = 0.f, aw = 0.f, dsum = 0.f;
#pragma unroll 2
    for (int j = g; j < cnt; j += 4) {
        int s = s_idx[dl16][j];                          // group broadcast
        float as2v = z2r[(size_t)s * 32 + 16];           // same 128B line
        float ev = as2v + adv;
        float w = __expf(LRELU(ev));
        float4 zv = *(const float4*)(z2r + (size_t)s * 32 + c * 4);
        ax += w * zv.x; ay += w * zv.y; az += w * zv.z; aw += w * zv.w;
        dsum += w;
    }
    // reconverged; merge the 4 edge groups (lane bits 2-3)
#pragma unroll
    for (int m = 4; m <= 8; m <<= 1) {
        ax += __shfl_xor(ax, m, 64); ay += __shfl_xor(ay, m, 64);
        az += __shfl_xor(az, m, 64); aw += __shfl_xor(aw, m, 64);
        dsum += __shfl_xor(dsum, m, 64);
    }
    if (g == 0 && d < N) {
        float inv = 1.f / dsum;
        float4 o = make_float4(ax * inv + b2[c * 4], ay * inv + b2[c * 4 + 1],
                               az * inv + b2[c * 4 + 2], aw * inv + b2[c * 4 + 3]);
        *(float4*)&out[(size_t)d * 16 + c * 4] = o;
    }
}

extern "C" void kernel_launch(void* const* d_in, const int* in_sizes, int n_in,
                              void* d_out, int out_size, void* d_ws, size_t ws_size,
                              hipStream_t stream) {
    const float* x      = (const float*)d_in[0];
    const int*   ei     = (const int*)d_in[1];
    const float* W1     = (const float*)d_in[2];
    const float* a_src1 = (const float*)d_in[3];
    const float* a_dst1 = (const float*)d_in[4];
    const float* b1     = (const float*)d_in[5];
    const float* W2     = (const float*)d_in[6];
    const float* a_src2 = (const float*)d_in[7];
    const float* a_dst2 = (const float*)d_in[8];
    const float* b2     = (const float*)d_in[9];
    float* out = (float*)d_out;

    const int N = in_sizes[0] / 128;   // 50000
    const int E = in_sizes[1] / 2;     // 850000
    const int* src = ei;
    const int* dst = ei + E;

    // Workspace (floats). z1h at 0; z2r at byte 8,000,000 (div 128 ✓) —
    // packed 32-float records [0:16]=z2,[16]=as2,[17]=ad2.
    float* ws = (float*)d_ws;
    size_t off = 0;
    __half* z1h = (__half*)(ws + off); off += (size_t)N * 32;  // N*64 halves
    float* ad1 = ws + off; off += (size_t)N * 8;
    float* z2r = ws + off; off += (size_t)N * 32;
    int* csr = (int*)(ws + off); off += (size_t)N * 64;   // 64-slot buckets
    int* deg = (int*)(ws + off); off += (size_t)N;        // written by kB
    int* pairs = (int*)(ws + off); off += (size_t)NB * BCAP;  // compact staging
    int* bcnt = (int*)(ws + off); off += NB;              // memset region

    hipMemsetAsync(bcnt, 0, (size_t)NB * sizeof(int), stream);

    // kA: 784 GEMM tile slots (782 used) + 196 partition ranks, interleaved
    kA<<<980, 256, 0, stream>>>(x, W1, a_dst1, src, dst, bcnt, pairs,
                                z1h, ad1, N, E);
    kB<<<NB, 256, 0, stream>>>(bcnt, pairs, deg, csr, N);
    kg1<<<(N + 15) / 16, 256, 0, stream>>>(deg, csr, a_src1, ad1, z1h, b1, W2,
                                           a_src2, a_dst2, z2r, N);
    kg2<<<(N + 15) / 16, 256, 0, stream>>>(deg, csr, z2r, b2, out, N);
}